// Round 1
// baseline (172.715 us; speedup 1.0000x reference)
//
#include <hip/hip_runtime.h>

#define A_DIM 1024
#define B_DIM 1024

__device__ __forceinline__ float wave_sum64(float v) {
    v += __shfl_xor(v, 1);
    v += __shfl_xor(v, 2);
    v += __shfl_xor(v, 4);
    v += __shfl_xor(v, 8);
    v += __shfl_xor(v, 16);
    v += __shfl_xor(v, 32);
    return v;
}

// ---------------------------------------------------------------------------
// Kernel 1: ha[a][d] = b1e[d] + sum_k nodes_a[a][k] * Wa[k][d]
//           hb[b][d] =          sum_k nodes_b[b][k] * Wb[k][d]
// Wa = W1e rows 32..63, Wb = W1e rows 64..95 (row-major, 16 cols)
// ---------------------------------------------------------------------------
__global__ __launch_bounds__(256) void prep_kernel(
    const float* __restrict__ na, const float* __restrict__ nb,
    const float* __restrict__ W1e, const float* __restrict__ b1e,
    float* __restrict__ ha, float* __restrict__ hb)
{
    int idx = blockIdx.x * 256 + threadIdx.x;   // 0..32767
    int half = idx >> 14;                       // 0 = a-side, 1 = b-side
    int r = (idx >> 4) & 1023;
    int d = idx & 15;
    const float* x = (half ? nb : na) + r * 32;
    const float* W = W1e + (half ? 64 * 16 : 32 * 16) + d;
    float acc = half ? 0.f : b1e[d];
    #pragma unroll
    for (int k = 0; k < 32; ++k) acc += x[k] * W[k * 16];
    (half ? hb : ha)[r * 16 + d] = acc;
}

// ---------------------------------------------------------------------------
// Kernel 2: fused edge MLP + latent store + both axis-sum partials.
// grid (16 btiles, 32 atiles), block 256 = 4 waves. Lane owns b = bbase+lane.
// Each wave handles 8 a-rows, 2 per iteration.
// ---------------------------------------------------------------------------
__global__ __launch_bounds__(256, 2) void edge_kernel(
    const float* __restrict__ E, const float* __restrict__ W1e,
    const float* __restrict__ W2e, const float* __restrict__ b2e,
    const float* __restrict__ ha, const float* __restrict__ hb,
    float* __restrict__ el_out, float* __restrict__ suma_p,
    float* __restrict__ sumb_p)
{
    __shared__ float4 We_s[32 * 4];   // We rows 0..31 of W1e
    __shared__ float4 W2_s[16 * 4];
    __shared__ float4 ha_s[32 * 4];
    __shared__ float  b2_s[16];
    __shared__ float4 sb_s[4][64][4];

    const int tid   = threadIdx.x;
    const int lane  = tid & 63;
    const int w     = tid >> 6;
    const int bt    = blockIdx.x;
    const int at    = blockIdx.y;
    const int bbase = bt * 64;
    const int abase = at * 32;

    for (int i = tid; i < 512; i += 256) ((float*)We_s)[i] = W1e[i];
    ((float*)W2_s)[tid < 256 ? tid : 0] = W2e[tid < 256 ? tid : 0];
    if (tid < 16) b2_s[tid] = b2e[tid];
    for (int i = tid; i < 512; i += 256) ((float*)ha_s)[i] = ha[abase * 16 + i];
    __syncthreads();

    const int b = bbase + lane;
    float hbl[16];
    {
        const float4* hp = (const float4*)(hb + b * 16);
        #pragma unroll
        for (int q = 0; q < 4; ++q) {
            float4 v = hp[q];
            hbl[q*4+0] = v.x; hbl[q*4+1] = v.y; hbl[q*4+2] = v.z; hbl[q*4+3] = v.w;
        }
    }
    float sumb[16];
    #pragma unroll
    for (int d = 0; d < 16; ++d) sumb[d] = 0.f;

    for (int i = 0; i < 4; ++i) {
        const int a0 = abase + w * 8 + i * 2;

        // load edge vectors for 2 edges (128 B each, contiguous per lane)
        float ev0[32], ev1[32];
        {
            const float4* p0 = (const float4*)(E + ((size_t)a0 * B_DIM + b) * 32);
            const float4* p1 = (const float4*)(E + ((size_t)(a0 + 1) * B_DIM + b) * 32);
            #pragma unroll
            for (int j = 0; j < 8; ++j) {
                float4 t = p0[j];
                ev0[4*j+0] = t.x; ev0[4*j+1] = t.y; ev0[4*j+2] = t.z; ev0[4*j+3] = t.w;
            }
            #pragma unroll
            for (int j = 0; j < 8; ++j) {
                float4 t = p1[j];
                ev1[4*j+0] = t.x; ev1[4*j+1] = t.y; ev1[4*j+2] = t.z; ev1[4*j+3] = t.w;
            }
        }

        // h = e @ We + ha[a] + hb[b]
        float h0[16], h1[16];
        #pragma unroll
        for (int q = 0; q < 4; ++q) {
            float4 va = ha_s[(a0 - abase) * 4 + q];
            float4 vb = ha_s[(a0 - abase + 1) * 4 + q];
            h0[q*4+0] = va.x + hbl[q*4+0]; h0[q*4+1] = va.y + hbl[q*4+1];
            h0[q*4+2] = va.z + hbl[q*4+2]; h0[q*4+3] = va.w + hbl[q*4+3];
            h1[q*4+0] = vb.x + hbl[q*4+0]; h1[q*4+1] = vb.y + hbl[q*4+1];
            h1[q*4+2] = vb.z + hbl[q*4+2]; h1[q*4+3] = vb.w + hbl[q*4+3];
        }
        #pragma unroll
        for (int k = 0; k < 32; ++k) {
            float ea = ev0[k], eb = ev1[k];
            #pragma unroll
            for (int q = 0; q < 4; ++q) {
                float4 wv = We_s[k * 4 + q];
                h0[q*4+0] += ea * wv.x; h0[q*4+1] += ea * wv.y;
                h0[q*4+2] += ea * wv.z; h0[q*4+3] += ea * wv.w;
                h1[q*4+0] += eb * wv.x; h1[q*4+1] += eb * wv.y;
                h1[q*4+2] += eb * wv.z; h1[q*4+3] += eb * wv.w;
            }
        }

        // el = relu(relu(h) @ W2e + b2e)
        float el0[16], el1[16];
        #pragma unroll
        for (int d = 0; d < 16; ++d) { el0[d] = b2_s[d]; el1[d] = b2_s[d]; }
        #pragma unroll
        for (int k = 0; k < 16; ++k) {
            float r0 = fmaxf(h0[k], 0.f), r1 = fmaxf(h1[k], 0.f);
            #pragma unroll
            for (int q = 0; q < 4; ++q) {
                float4 wv = W2_s[k * 4 + q];
                el0[q*4+0] += r0 * wv.x; el0[q*4+1] += r0 * wv.y;
                el0[q*4+2] += r0 * wv.z; el0[q*4+3] += r0 * wv.w;
                el1[q*4+0] += r1 * wv.x; el1[q*4+1] += r1 * wv.y;
                el1[q*4+2] += r1 * wv.z; el1[q*4+3] += r1 * wv.w;
            }
        }
        #pragma unroll
        for (int d = 0; d < 16; ++d) {
            el0[d] = fmaxf(el0[d], 0.f);
            el1[d] = fmaxf(el1[d], 0.f);
            sumb[d] += el0[d] + el1[d];
        }

        // store latent (64 B per edge, contiguous per lane)
        {
            float4* o0 = (float4*)(el_out + ((size_t)a0 * B_DIM + b) * 16);
            float4* o1 = (float4*)(el_out + ((size_t)(a0 + 1) * B_DIM + b) * 16);
            #pragma unroll
            for (int q = 0; q < 4; ++q) {
                o0[q] = make_float4(el0[q*4+0], el0[q*4+1], el0[q*4+2], el0[q*4+3]);
                o1[q] = make_float4(el1[q*4+0], el1[q*4+1], el1[q*4+2], el1[q*4+3]);
            }
        }

        // suma: reduce el over the 64 lanes (all-lanes butterfly), lane 0 stores
        float r0[16], r1[16];
        #pragma unroll
        for (int d = 0; d < 16; ++d) {
            r0[d] = wave_sum64(el0[d]);
            r1[d] = wave_sum64(el1[d]);
        }
        if (lane == 0) {
            float4* s0 = (float4*)(suma_p + ((size_t)bt * A_DIM + a0) * 16);
            #pragma unroll
            for (int q = 0; q < 4; ++q) {
                s0[q]     = make_float4(r0[q*4+0], r0[q*4+1], r0[q*4+2], r0[q*4+3]);
                s0[q + 4] = make_float4(r1[q*4+0], r1[q*4+1], r1[q*4+2], r1[q*4+3]);
            }
        }
    }

    // sumb: combine the 4 waves' per-b partials, store per-(atile,b) partial
    #pragma unroll
    for (int q = 0; q < 4; ++q)
        sb_s[w][lane][q] = make_float4(sumb[q*4+0], sumb[q*4+1], sumb[q*4+2], sumb[q*4+3]);
    __syncthreads();
    {
        int bl = tid >> 2, dq = tid & 3;
        float4 v0 = sb_s[0][bl][dq], v1 = sb_s[1][bl][dq];
        float4 v2 = sb_s[2][bl][dq], v3 = sb_s[3][bl][dq];
        float4 s = make_float4(v0.x + v1.x + v2.x + v3.x, v0.y + v1.y + v2.y + v3.y,
                               v0.z + v1.z + v2.z + v3.z, v0.w + v1.w + v2.w + v3.w);
        ((float4*)(sumb_p + ((size_t)at * B_DIM + bbase + bl) * 16))[dq] = s;
    }
}

// ---------------------------------------------------------------------------
// Kernel 3: deterministic reduction of the partials.
// ---------------------------------------------------------------------------
__global__ __launch_bounds__(256) void reduce_kernel(
    const float* __restrict__ suma_p, const float* __restrict__ sumb_p,
    float* __restrict__ suma, float* __restrict__ sumb)
{
    int idx = blockIdx.x * 256 + threadIdx.x;   // 0..32767
    if (idx < 16384) {
        float acc = 0.f;
        #pragma unroll
        for (int t = 0; t < 16; ++t) acc += suma_p[t * 16384 + idx];
        suma[idx] = acc;
    } else {
        int j = idx - 16384;
        float acc = 0.f;
        #pragma unroll
        for (int t = 0; t < 32; ++t) acc += sumb_p[t * 16384 + j];
        sumb[j] = acc;
    }
}

// ---------------------------------------------------------------------------
// Kernel 4: node MLP for both sides. 2048 rows, block = 8 rows x 32 cols.
// ---------------------------------------------------------------------------
__global__ __launch_bounds__(256) void node_kernel(
    const float* __restrict__ na, const float* __restrict__ nb,
    const float* __restrict__ suma, const float* __restrict__ sumb,
    const float* __restrict__ W1n, const float* __restrict__ b1n,
    const float* __restrict__ W2n, const float* __restrict__ b2n,
    float* __restrict__ out_a, float* __restrict__ out_b)
{
    __shared__ float W1_s[48 * 32];
    __shared__ float W2_s[32 * 32];
    __shared__ float hid_s[8][32];
    int tid = threadIdx.x;
    for (int i = tid; i < 1536; i += 256) W1_s[i] = W1n[i];
    for (int i = tid; i < 1024; i += 256) W2_s[i] = W2n[i];
    __syncthreads();
    int rlocal = tid >> 5;
    int r = blockIdx.x * 8 + rlocal;
    int j = tid & 31;
    int isb = (r >= 1024);
    int rr = isb ? r - 1024 : r;
    const float* nx = (isb ? nb : na) + rr * 32;
    const float* sx = (isb ? sumb : suma) + rr * 16;
    float acc = b1n[j];
    #pragma unroll
    for (int k = 0; k < 32; ++k) acc += nx[k] * W1_s[k * 32 + j];
    #pragma unroll
    for (int k = 0; k < 16; ++k) acc += sx[k] * W1_s[(32 + k) * 32 + j];
    hid_s[rlocal][j] = fmaxf(acc, 0.f);
    __syncthreads();
    float acc2 = b2n[j];
    #pragma unroll
    for (int k = 0; k < 32; ++k) acc2 += hid_s[rlocal][k] * W2_s[k * 32 + j];
    (isb ? out_b : out_a)[rr * 32 + j] = fmaxf(acc2, 0.f);
}

extern "C" void kernel_launch(void* const* d_in, const int* in_sizes, int n_in,
                              void* d_out, int out_size, void* d_ws, size_t ws_size,
                              hipStream_t stream)
{
    const float* E   = (const float*)d_in[0];
    const float* na  = (const float*)d_in[1];
    const float* nb  = (const float*)d_in[2];
    const float* W1e = (const float*)d_in[3];
    const float* b1e = (const float*)d_in[4];
    const float* W2e = (const float*)d_in[5];
    const float* b2e = (const float*)d_in[6];
    const float* W1n = (const float*)d_in[7];
    const float* b1n = (const float*)d_in[8];
    const float* W2n = (const float*)d_in[9];
    const float* b2n = (const float*)d_in[10];

    float* out    = (float*)d_out;
    float* el_out = out;
    float* out_a  = out + (size_t)A_DIM * B_DIM * 16;
    float* out_b  = out_a + A_DIM * 32;

    float* ws     = (float*)d_ws;
    float* ha     = ws;                      // 16384
    float* hb     = ws + 16384;              // 16384
    float* suma_p = ws + 32768;              // 16 * 16384
    float* sumb_p = suma_p + 16 * 16384;     // 32 * 16384
    float* suma   = sumb_p + 32 * 16384;     // 16384
    float* sumb   = suma + 16384;            // 16384

    hipLaunchKernelGGL(prep_kernel, dim3(128), dim3(256), 0, stream,
                       na, nb, W1e, b1e, ha, hb);
    hipLaunchKernelGGL(edge_kernel, dim3(16, 32), dim3(256), 0, stream,
                       E, W1e, W2e, b2e, ha, hb, el_out, suma_p, sumb_p);
    hipLaunchKernelGGL(reduce_kernel, dim3(128), dim3(256), 0, stream,
                       suma_p, sumb_p, suma, sumb);
    hipLaunchKernelGGL(node_kernel, dim3(256), dim3(256), 0, stream,
                       na, nb, suma, sumb, W1n, b1n, W2n, b2n, out_a, out_b);
}

// Round 2
// 58.706 us; speedup vs baseline: 2.9420x; 2.9420x over previous
//
#include <hip/hip_runtime.h>

#define A_DIM 1024
#define B_DIM 1024

typedef __attribute__((ext_vector_type(8))) short bfrag8;
typedef __attribute__((ext_vector_type(4))) float facc4;

__device__ __forceinline__ unsigned short f2bf(float f) {
    unsigned u = __float_as_uint(f);
    u = (u + 0x7FFFu + ((u >> 16) & 1u)) >> 16;
    return (unsigned short)u;
}
__device__ __forceinline__ unsigned cvtpk(float lo, float hi) {
    unsigned r;
    asm("v_cvt_pk_bf16_f32 %0, %1, %2" : "=v"(r) : "v"(lo), "v"(hi));
    return r;
}

// ---------------------------------------------------------------------------
// Kernel 1: ha[a][d] = b1e[d] + sum_k nodes_a[a][k] * Wa[k][d]
//           hb[b][d] =          sum_k nodes_b[b][k] * Wb[k][d]
// ---------------------------------------------------------------------------
__global__ __launch_bounds__(256) void prep_kernel(
    const float* __restrict__ na, const float* __restrict__ nb,
    const float* __restrict__ W1e, const float* __restrict__ b1e,
    float* __restrict__ ha, float* __restrict__ hb)
{
    int idx = blockIdx.x * 256 + threadIdx.x;   // 0..32767
    int half = idx >> 14;                       // 0 = a-side, 1 = b-side
    int r = (idx >> 4) & 1023;
    int d = idx & 15;
    const float* x = (half ? nb : na) + r * 32;
    const float* W = W1e + (half ? 64 * 16 : 32 * 16) + d;
    float acc = half ? 0.f : b1e[d];
    #pragma unroll
    for (int k = 0; k < 32; ++k) acc += x[k] * W[k * 16];
    (half ? hb : ha)[r * 16 + d] = acc;
}

// ---------------------------------------------------------------------------
// Kernel 2: fused edge MLP via MFMA.
// Block = 512 threads = 8 waves. Block owns 64 b's (bg) x 32 a's (at).
// Wave w handles a = abase + w*4 + i (i=0..3), 64 edges (b's) per iter.
// Layer1: D1[d][edge] = mfma(A=We^T frag in regs, B=E-tile from LDS, C=ha+hb)
// Layer2: D2[d2][edge] = mfma(A=W2^T frag (K padded to 32), B=relu(h) via shfl)
// C/D layout: col = lane&15 (edge), row = (lane>>4)*4 + reg (d).
// A/B frag: 16-dim = lane&15, k = (lane>>4)*8 + t.
// ---------------------------------------------------------------------------
__global__ __launch_bounds__(512, 4) void edge_kernel(
    const float* __restrict__ E, const float* __restrict__ W1e,
    const float* __restrict__ W2e, const float* __restrict__ b2e,
    const float* __restrict__ ha, const float* __restrict__ hb,
    float* __restrict__ el_out, float* __restrict__ suma_p,
    float* __restrict__ sumb_p)
{
    // bytes [0,32768): 8 waves x 4KB bf16 staging (reused for sumb combine)
    // floats [8192,8704): ha tile (32 a x 16 d)
    __shared__ __align__(16) float smem[8704];
    const int tid  = threadIdx.x;
    const int lane = tid & 63;
    const int w    = tid >> 6;              // 0..7
    const int n    = lane & 15;             // edge-in-tile / weight d-col
    const int g    = lane >> 4;             // 0..3  k-chunk / d-row group
    const int bg   = blockIdx.x;            // 0..15
    const int at   = blockIdx.y;            // 0..31
    const int bbase = bg * 64;
    const int abase = at * 32;

    smem[8192 + tid] = ha[abase * 16 + tid];
    __syncthreads();

    // ---- persistent fragments (weights transposed: A[m][k] = W[k][m]) ----
    bfrag8 w1f, w2f;
    #pragma unroll
    for (int t = 0; t < 8; ++t) {
        w1f[t] = (short)f2bf(W1e[(g * 8 + t) * 16 + n]);
        w2f[t] = (g < 2) ? (short)f2bf(W2e[(g * 8 + t) * 16 + n]) : (short)0;
    }
    facc4 hbF[4];
    #pragma unroll
    for (int mt = 0; mt < 4; ++mt)
        hbF[mt] = *(const facc4*)&hb[(bbase + mt * 16 + n) * 16 + g * 4];
    facc4 b2f = *(const facc4*)&b2e[g * 4];

    facc4 sumbA[4];
    #pragma unroll
    for (int mt = 0; mt < 4; ++mt) sumbA[mt] = facc4{0.f, 0.f, 0.f, 0.f};

    // staging addresses (wave-private 4KB, XOR-swizzled 16B slots)
    char* sbase = (char*)smem + w * 4096;
    const int q3 = lane >> 3, jj = lane & 7;
    char* wptr = sbase + q3 * 64 + ((((jj >> 1) ^ (q3 >> 1)) & 3) << 4) + ((jj & 1) << 3);
    const char* rptr = sbase + n * 64 + ((g ^ ((n >> 1) & 3)) << 4);

    // prologue: load iter 0 tile (fully coalesced: lane L takes chunk t*64+L)
    float4 gbuf[8];
    {
        const float4* p = (const float4*)(E + ((size_t)(abase + w * 4) * B_DIM + bbase) * 32);
        #pragma unroll
        for (int t = 0; t < 8; ++t) gbuf[t] = p[t * 64 + lane];
    }

    #pragma unroll
    for (int i = 0; i < 4; ++i) {
        const int a = abase + w * 4 + i;

        // stage iter i (f32 -> bf16, swizzled ds_write_b64)
        #pragma unroll
        for (int t = 0; t < 8; ++t) {
            unsigned lo = cvtpk(gbuf[t].x, gbuf[t].y);
            unsigned hi = cvtpk(gbuf[t].z, gbuf[t].w);
            *(uint2*)(wptr + t * 512) = make_uint2(lo, hi);
        }
        // prefetch iter i+1 into registers (covers HBM latency under compute)
        if (i < 3) {
            const float4* p = (const float4*)(E + ((size_t)(a + 1) * B_DIM + bbase) * 32);
            #pragma unroll
            for (int t = 0; t < 8; ++t) gbuf[t] = p[t * 64 + lane];
        }

        facc4 haf = *(const facc4*)&smem[8192 + (w * 4 + i) * 16 + g * 4];

        // layer 1: 4 MFMAs (one per 16-edge tile)
        facc4 acc[4];
        #pragma unroll
        for (int mt = 0; mt < 4; ++mt) {
            bfrag8 ef = *(const bfrag8*)(rptr + mt * 1024);
            acc[mt] = __builtin_amdgcn_mfma_f32_16x16x32_bf16(
                w1f, ef, haf + hbF[mt], 0, 0, 0);
        }

        facc4 ssum = facc4{0.f, 0.f, 0.f, 0.f};
        #pragma unroll
        for (int mt = 0; mt < 4; ++mt) {
            facc4 h = acc[mt];
            h.x = fmaxf(h.x, 0.f); h.y = fmaxf(h.y, 0.f);
            h.z = fmaxf(h.z, 0.f); h.w = fmaxf(h.w, 0.f);
            // transpose relu(h) (row=d,col=edge) -> layer2 B-frag
            // lane needs k=d in [g*8,g*8+8) of its edge col n:
            // from lanes n+32g (regs 0..3) and n+32g+16 (regs 0..3)
            const int sl = (n + g * 32) & 63;
            const int sh = (n + g * 32 + 16) & 63;
            float v0 = __shfl(h.x, sl), v1 = __shfl(h.y, sl);
            float v2 = __shfl(h.z, sl), v3 = __shfl(h.w, sl);
            float u0 = __shfl(h.x, sh), u1 = __shfl(h.y, sh);
            float u2 = __shfl(h.z, sh), u3 = __shfl(h.w, sh);
            union { unsigned u[4]; bfrag8 s; } bb;
            bb.u[0] = cvtpk(v0, v1); bb.u[1] = cvtpk(v2, v3);
            bb.u[2] = cvtpk(u0, u1); bb.u[3] = cvtpk(u2, u3);
            facc4 e = __builtin_amdgcn_mfma_f32_16x16x32_bf16(w2f, bb.s, b2f, 0, 0, 0);
            e.x = fmaxf(e.x, 0.f); e.y = fmaxf(e.y, 0.f);
            e.z = fmaxf(e.z, 0.f); e.w = fmaxf(e.w, 0.f);
            // coalesced: lanes (g,n) cover 1KB contiguous per mt
            *(facc4*)&el_out[((size_t)a * B_DIM + bbase + mt * 16 + n) * 16 + g * 4] = e;
            sumbA[mt] += e;
            ssum += e;
        }
        // suma: butterfly over the 16 edge-cols (lanes sharing g)
        #pragma unroll
        for (int m = 1; m <= 8; m <<= 1) {
            ssum.x += __shfl_xor(ssum.x, m);
            ssum.y += __shfl_xor(ssum.y, m);
            ssum.z += __shfl_xor(ssum.z, m);
            ssum.w += __shfl_xor(ssum.w, m);
        }
        if (n == 0)
            *(facc4*)&suma_p[((size_t)bg * A_DIM + a) * 16 + g * 4] = ssum;
    }

    // ---- combine sumb across the 8 waves (reuse staging LDS) ----
    __syncthreads();
    #pragma unroll
    for (int mt = 0; mt < 4; ++mt)
        ((facc4*)smem)[(w * 64 + mt * 16 + n) * 4 + g] = sumbA[mt];
    __syncthreads();
    if (tid < 256) {
        const int bl = tid >> 2, q = tid & 3;
        facc4 s = facc4{0.f, 0.f, 0.f, 0.f};
        #pragma unroll
        for (int ww = 0; ww < 8; ++ww) s += ((facc4*)smem)[(ww * 64 + bl) * 4 + q];
        *(facc4*)&sumb_p[((size_t)at * B_DIM + bbase + bl) * 16 + q * 4] = s;
    }
}

// ---------------------------------------------------------------------------
// Kernel 3: deterministic reduction of the partials.
// ---------------------------------------------------------------------------
__global__ __launch_bounds__(256) void reduce_kernel(
    const float* __restrict__ suma_p, const float* __restrict__ sumb_p,
    float* __restrict__ suma, float* __restrict__ sumb)
{
    int idx = blockIdx.x * 256 + threadIdx.x;   // 0..32767
    if (idx < 16384) {
        float acc = 0.f;
        #pragma unroll
        for (int t = 0; t < 16; ++t) acc += suma_p[t * 16384 + idx];
        suma[idx] = acc;
    } else {
        int j = idx - 16384;
        float acc = 0.f;
        #pragma unroll
        for (int t = 0; t < 32; ++t) acc += sumb_p[t * 16384 + j];
        sumb[j] = acc;
    }
}

// ---------------------------------------------------------------------------
// Kernel 4: node MLP for both sides. 2048 rows, block = 8 rows x 32 cols.
// ---------------------------------------------------------------------------
__global__ __launch_bounds__(256) void node_kernel(
    const float* __restrict__ na, const float* __restrict__ nb,
    const float* __restrict__ suma, const float* __restrict__ sumb,
    const float* __restrict__ W1n, const float* __restrict__ b1n,
    const float* __restrict__ W2n, const float* __restrict__ b2n,
    float* __restrict__ out_a, float* __restrict__ out_b)
{
    __shared__ float W1_s[48 * 32];
    __shared__ float W2_s[32 * 32];
    __shared__ float hid_s[8][32];
    int tid = threadIdx.x;
    for (int i = tid; i < 1536; i += 256) W1_s[i] = W1n[i];
    for (int i = tid; i < 1024; i += 256) W2_s[i] = W2n[i];
    __syncthreads();
    int rlocal = tid >> 5;
    int r = blockIdx.x * 8 + rlocal;
    int j = tid & 31;
    int isb = (r >= 1024);
    int rr = isb ? r - 1024 : r;
    const float* nx = (isb ? nb : na) + rr * 32;
    const float* sx = (isb ? sumb : suma) + rr * 16;
    float acc = b1n[j];
    #pragma unroll
    for (int k = 0; k < 32; ++k) acc += nx[k] * W1_s[k * 32 + j];
    #pragma unroll
    for (int k = 0; k < 16; ++k) acc += sx[k] * W1_s[(32 + k) * 32 + j];
    hid_s[rlocal][j] = fmaxf(acc, 0.f);
    __syncthreads();
    float acc2 = b2n[j];
    #pragma unroll
    for (int k = 0; k < 32; ++k) acc2 += hid_s[rlocal][k] * W2_s[k * 32 + j];
    (isb ? out_b : out_a)[rr * 32 + j] = fmaxf(acc2, 0.f);
}

extern "C" void kernel_launch(void* const* d_in, const int* in_sizes, int n_in,
                              void* d_out, int out_size, void* d_ws, size_t ws_size,
                              hipStream_t stream)
{
    const float* E   = (const float*)d_in[0];
    const float* na  = (const float*)d_in[1];
    const float* nb  = (const float*)d_in[2];
    const float* W1e = (const float*)d_in[3];
    const float* b1e = (const float*)d_in[4];
    const float* W2e = (const float*)d_in[5];
    const float* b2e = (const float*)d_in[6];
    const float* W1n = (const float*)d_in[7];
    const float* b1n = (const float*)d_in[8];
    const float* W2n = (const float*)d_in[9];
    const float* b2n = (const float*)d_in[10];

    float* out    = (float*)d_out;
    float* el_out = out;
    float* out_a  = out + (size_t)A_DIM * B_DIM * 16;
    float* out_b  = out_a + A_DIM * 32;

    float* ws     = (float*)d_ws;
    float* ha     = ws;                      // 16384
    float* hb     = ws + 16384;              // 16384
    float* suma_p = ws + 32768;              // 16 * 16384
    float* sumb_p = suma_p + 16 * 16384;     // 32 * 16384
    float* suma   = sumb_p + 32 * 16384;     // 16384
    float* sumb   = suma + 16384;            // 16384

    hipLaunchKernelGGL(prep_kernel, dim3(128), dim3(256), 0, stream,
                       na, nb, W1e, b1e, ha, hb);
    hipLaunchKernelGGL(edge_kernel, dim3(16, 32), dim3(512), 0, stream,
                       E, W1e, W2e, b2e, ha, hb, el_out, suma_p, sumb_p);
    hipLaunchKernelGGL(reduce_kernel, dim3(128), dim3(256), 0, stream,
                       suma_p, sumb_p, suma, sumb);
    hipLaunchKernelGGL(node_kernel, dim3(256), dim3(256), 0, stream,
                       na, nb, suma, sumb, W1n, b1n, W2n, b2n, out_a, out_b);
}